// Round 1
// baseline (285.186 us; speedup 1.0000x reference)
//
#include <hip/hip_runtime.h>
#include <cstdint>

#define SEQ    8192
#define DIN    1024
#define DOUT   128
#define NSPLIT 4
#define KVTILE 64
#define SM_SCALE 0.08838834764831845f   // 1/sqrt(128)
#define LOG2E    1.4426950408889634f

typedef unsigned short u16;
typedef __bf16 bf16x8 __attribute__((ext_vector_type(8)));
typedef float  f32x4  __attribute__((ext_vector_type(4)));
typedef unsigned short u16x8 __attribute__((ext_vector_type(8)));
typedef unsigned short u16x4 __attribute__((ext_vector_type(4)));

// round-to-nearest-even f32 -> bf16
__device__ __forceinline__ u16 f2bf(float f) {
  union { float f; uint32_t u; } c; c.f = f;
  uint32_t u = c.u;
  return (u16)((u + 0x7FFFu + ((u >> 16) & 1u)) >> 16);
}

__device__ __forceinline__ bf16x8 ldsu8(const u16* base, int byteoff) {
  return __builtin_bit_cast(bf16x8,
    *reinterpret_cast<const u16x8*>(reinterpret_cast<const char*>(base) + byteoff));
}
__device__ __forceinline__ bf16x8 glbu8(const u16* p) {
  return __builtin_bit_cast(bf16x8, *reinterpret_cast<const u16x8*>(p));
}

// ---------------------------------------------------------------- kernel 0
// W [1024][128] fp32  ->  Wt [3][128][1024] bf16 (transposed)
__global__ __launch_bounds__(256) void k_wtrans(const float* __restrict__ wq,
                                                const float* __restrict__ wk,
                                                const float* __restrict__ wv,
                                                u16* __restrict__ Wt) {
  const float* w = (blockIdx.y == 0) ? wq : (blockIdx.y == 1) ? wk : wv;
  int idx = blockIdx.x * 256 + threadIdx.x;      // over DIN*DOUT
  int k = idx >> 7, n = idx & 127;
  Wt[(size_t)blockIdx.y * (DOUT * DIN) + (size_t)n * DIN + k] = f2bf(w[idx]);
}

// ---------------------------------------------------------------- kernel 1
// Q = X Wq, K = X Wk, V = X Wv.  Q,K row-major bf16 [SEQ][128]; V transposed
// bf16 [128][SEQ].  Block: 128 threads (2 waves), M-tile 32, grid 256.
__global__ __launch_bounds__(128) void k_qkv(const float* __restrict__ x,
                                             const u16* __restrict__ Wt,
                                             u16* __restrict__ Q,
                                             u16* __restrict__ K,
                                             u16* __restrict__ Vt) {
  __shared__ __attribute__((aligned(16))) u16 Xs[32 * 64];   // swizzled, 4 KB
  const int tid  = threadIdx.x;
  const int lane = tid & 63, wave = tid >> 6;
  const int lm   = lane & 15, g = lane >> 4;
  const int m0   = blockIdx.x * 32;

  f32x4 acc[3][8];
#pragma unroll
  for (int w = 0; w < 3; ++w)
#pragma unroll
    for (int nb = 0; nb < 8; ++nb) acc[w][nb] = (f32x4){0.f, 0.f, 0.f, 0.f};

  for (int kc = 0; kc < DIN / 64; ++kc) {
    __syncthreads();
    // stage X tile [32 rows][64 k] fp32 -> bf16, XOR-swizzled rows (stride 128B)
#pragma unroll
    for (int p = 0; p < 4; ++p) {
      int row = p * 8 + (tid >> 4);
      int c4  = (tid & 15) * 4;
      float4 v = *reinterpret_cast<const float4*>(
          x + (size_t)(m0 + row) * DIN + kc * 64 + c4);
      u16x4 b = { f2bf(v.x), f2bf(v.y), f2bf(v.z), f2bf(v.w) };
      *reinterpret_cast<u16x4*>(reinterpret_cast<char*>(Xs) + row * 128 +
                                ((c4 * 2) ^ ((row & 7) << 4))) = b;
    }
    __syncthreads();

    const int mrow = wave * 16 + lm;
    bf16x8 a[2];
#pragma unroll
    for (int t = 0; t < 2; ++t)
      a[t] = ldsu8(Xs, mrow * 128 + (((t * 32 + 8 * g) * 2) ^ ((mrow & 7) << 4)));

#pragma unroll
    for (int w = 0; w < 3; ++w) {
#pragma unroll
      for (int nb = 0; nb < 8; ++nb) {
        int n = nb * 16 + lm;
        const u16* wp = Wt + (size_t)w * (DOUT * DIN) + (size_t)n * DIN +
                        kc * 64 + 8 * g;
#pragma unroll
        for (int t = 0; t < 2; ++t) {
          bf16x8 b = glbu8(wp + t * 32);
          acc[w][nb] =
              __builtin_amdgcn_mfma_f32_16x16x32_bf16(a[t], b, acc[w][nb], 0, 0, 0);
        }
      }
    }
  }

  // epilogue: C/D layout col=lane&15, row=(lane>>4)*4+reg  [HW-verified]
#pragma unroll
  for (int nb = 0; nb < 8; ++nb)
#pragma unroll
    for (int r = 0; r < 4; ++r) {
      int m = m0 + wave * 16 + g * 4 + r;
      int n = nb * 16 + lm;
      Q[(size_t)m * DOUT + n] = f2bf(acc[0][nb][r]);
      K[(size_t)m * DOUT + n] = f2bf(acc[1][nb][r]);
      Vt[(size_t)n * SEQ + m] = f2bf(acc[2][nb][r]);
    }
}

// ---------------------------------------------------------------- kernel 2
// Flash attention partials. Block 256 (4 waves), Q-tile 64 (16 rows/wave),
// KV-tile 64 staged in LDS (XOR-swizzled). grid (SEQ/64, NSPLIT).
__global__ __launch_bounds__(256) void k_attn(const u16* __restrict__ Q,
                                              const u16* __restrict__ K,
                                              const u16* __restrict__ Vt,
                                              float* __restrict__ Op,
                                              float* __restrict__ Mb,
                                              float* __restrict__ Lb) {
  __shared__ __attribute__((aligned(16))) u16 Ks[64 * 128];    // 16 KB
  __shared__ __attribute__((aligned(16))) u16 Vts[128 * 64];   // 16 KB
  __shared__ __attribute__((aligned(16))) u16 Ps[4][16 * 64];  //  8 KB
  const int tid  = threadIdx.x;
  const int lane = tid & 63, wave = tid >> 6;
  const int lm   = lane & 15, g = lane >> 4;
  const int m0   = blockIdx.x * 64;
  const int split = blockIdx.y;
  const int kvbase = split * (SEQ / NSPLIT);

  // Q fragments, resident in registers for the whole kernel
  bf16x8 qf[4];
  {
    const u16* qp = Q + (size_t)(m0 + wave * 16 + lm) * DOUT + 8 * g;
#pragma unroll
    for (int t = 0; t < 4; ++t) qf[t] = glbu8(qp + t * 32);
  }

  f32x4 o[8];
#pragma unroll
  for (int nb = 0; nb < 8; ++nb) o[nb] = (f32x4){0.f, 0.f, 0.f, 0.f};
  float mr[4] = {-1e30f, -1e30f, -1e30f, -1e30f};
  float lr[4] = {0.f, 0.f, 0.f, 0.f};

  for (int it = 0; it < (SEQ / NSPLIT) / KVTILE; ++it) {
    const int kv0 = kvbase + it * KVTILE;
    __syncthreads();
    // stage K tile [64][128] (row stride 256B, swizzle granule = 16B)
#pragma unroll
    for (int p = 0; p < 4; ++p) {
      int row = p * 16 + (tid >> 4), gg = tid & 15;
      u16x8 v = *reinterpret_cast<const u16x8*>(
          K + (size_t)(kv0 + row) * DOUT + gg * 8);
      *reinterpret_cast<u16x8*>(reinterpret_cast<char*>(Ks) + row * 256 +
                                ((gg * 16) ^ ((row & 7) << 4))) = v;
    }
    // stage V^T tile [128][64] (row stride 128B)
#pragma unroll
    for (int p = 0; p < 4; ++p) {
      int n = p * 32 + (tid >> 3), gg = tid & 7;
      u16x8 v = *reinterpret_cast<const u16x8*>(
          Vt + (size_t)n * SEQ + kv0 + gg * 8);
      *reinterpret_cast<u16x8*>(reinterpret_cast<char*>(Vts) + n * 128 +
                                ((gg * 16) ^ ((n & 7) << 4))) = v;
    }
    __syncthreads();

    // ---- S = Q K^T * scale  (4 col-blocks x K=128)
    f32x4 s[4];
#pragma unroll
    for (int cb = 0; cb < 4; ++cb) {
      f32x4 a = (f32x4){0.f, 0.f, 0.f, 0.f};
      int krow = cb * 16 + lm;
#pragma unroll
      for (int t = 0; t < 4; ++t) {
        bf16x8 b = ldsu8(Ks, krow * 256 +
                             (((t * 32 + 8 * g) * 2) ^ ((krow & 7) << 4)));
        a = __builtin_amdgcn_mfma_f32_16x16x32_bf16(qf[t], b, a, 0, 0, 0);
      }
      s[cb] = a * SM_SCALE;
    }

    // ---- online softmax (rows owned by lane: g*4+r; reduce over 16 lanes)
    float pv[4][4];
#pragma unroll
    for (int r = 0; r < 4; ++r) {
      float rm = fmaxf(fmaxf(s[0][r], s[1][r]), fmaxf(s[2][r], s[3][r]));
#pragma unroll
      for (int off = 1; off < 16; off <<= 1) rm = fmaxf(rm, __shfl_xor(rm, off));
      float mn = fmaxf(mr[r], rm);
      float alpha = exp2f((mr[r] - mn) * LOG2E);
      float rs = 0.f;
#pragma unroll
      for (int cb = 0; cb < 4; ++cb) {
        float p = exp2f((s[cb][r] - mn) * LOG2E);
        pv[cb][r] = p;
        rs += p;
      }
#pragma unroll
      for (int off = 1; off < 16; off <<= 1) rs += __shfl_xor(rs, off);
      lr[r] = lr[r] * alpha + rs;
      mr[r] = mn;
#pragma unroll
      for (int nb = 0; nb < 8; ++nb) o[nb][r] *= alpha;
    }

    // ---- P -> per-wave LDS (bf16), swizzled like the others
    u16* pw = Ps[wave];
#pragma unroll
    for (int cb = 0; cb < 4; ++cb)
#pragma unroll
      for (int r = 0; r < 4; ++r) {
        int row = g * 4 + r, col = cb * 16 + lm;
        *reinterpret_cast<u16*>(reinterpret_cast<char*>(pw) + row * 128 +
                                ((col * 2) ^ ((row & 7) << 4))) = f2bf(pv[cb][r]);
      }
    __syncthreads();   // orders P writes before P reads (and is uniform)

    // ---- O += P V   (A = P rows, B = V^T rows = d-columns)
#pragma unroll
    for (int t = 0; t < 2; ++t) {
      bf16x8 pa = ldsu8(pw, lm * 128 +
                            (((t * 32 + 8 * g) * 2) ^ ((lm & 7) << 4)));
#pragma unroll
      for (int nb = 0; nb < 8; ++nb) {
        int vrow = nb * 16 + lm;
        bf16x8 vb = ldsu8(Vts, vrow * 128 +
                              (((t * 32 + 8 * g) * 2) ^ ((vrow & 7) << 4)));
        o[nb] = __builtin_amdgcn_mfma_f32_16x16x32_bf16(pa, vb, o[nb], 0, 0, 0);
      }
    }
  }

  // ---- store partials
  const size_t ob = (size_t)split * SEQ * DOUT;
#pragma unroll
  for (int nb = 0; nb < 8; ++nb)
#pragma unroll
    for (int r = 0; r < 4; ++r) {
      int m = m0 + wave * 16 + g * 4 + r;
      Op[ob + (size_t)m * DOUT + nb * 16 + lm] = o[nb][r];
    }
  if (lm == 0) {
#pragma unroll
    for (int r = 0; r < 4; ++r) {
      int m = m0 + wave * 16 + g * 4 + r;
      Mb[split * SEQ + m] = mr[r];
      Lb[split * SEQ + m] = lr[r];
    }
  }
}

// ---------------------------------------------------------------- kernel 3
__global__ __launch_bounds__(256) void k_combine(const float* __restrict__ Op,
                                                 const float* __restrict__ Mb,
                                                 const float* __restrict__ Lb,
                                                 float* __restrict__ out) {
  int idx = blockIdx.x * 256 + threadIdx.x;   // over SEQ*DOUT
  int srow = idx >> 7;
  float m0 = Mb[srow], m1 = Mb[SEQ + srow], m2 = Mb[2 * SEQ + srow],
        m3 = Mb[3 * SEQ + srow];
  float M = fmaxf(fmaxf(m0, m1), fmaxf(m2, m3));
  float e0 = exp2f((m0 - M) * LOG2E), e1 = exp2f((m1 - M) * LOG2E);
  float e2 = exp2f((m2 - M) * LOG2E), e3 = exp2f((m3 - M) * LOG2E);
  float denom = Lb[srow] * e0 + Lb[SEQ + srow] * e1 + Lb[2 * SEQ + srow] * e2 +
                Lb[3 * SEQ + srow] * e3;
  const size_t st = (size_t)SEQ * DOUT;
  float num = Op[idx] * e0 + Op[st + idx] * e1 + Op[2 * st + idx] * e2 +
              Op[3 * st + idx] * e3;
  out[idx] = num / denom;
}

// ---------------------------------------------------------------- launch
extern "C" void kernel_launch(void* const* d_in, const int* in_sizes, int n_in,
                              void* d_out, int out_size, void* d_ws, size_t ws_size,
                              hipStream_t stream) {
  const float* x  = (const float*)d_in[0];
  const float* wq = (const float*)d_in[1];
  const float* wk = (const float*)d_in[2];
  const float* wv = (const float*)d_in[3];
  char* ws = (char*)d_ws;

  // workspace layout (bytes):
  //  [0,       0xC0000)   Wt bf16 [3][128][1024]
  //  [1 MiB,   3 MiB)     Q  bf16 [8192][128]
  //  [3 MiB,   5 MiB)     K  bf16 [8192][128]
  //  [5 MiB,   7 MiB)     Vt bf16 [128][8192]
  //  [7 MiB,  23 MiB)     Op f32 [4][8192][128]
  //  [23 MiB, +128 KiB)   Mb f32 [4][8192]
  //  [.. ,    +128 KiB)   Lb f32 [4][8192]      total ~23.25 MiB
  u16*   Wt = (u16*)(ws);
  u16*   Q  = (u16*)(ws + (size_t)(1u << 20));
  u16*   K  = (u16*)(ws + (size_t)(3u << 20));
  u16*   Vt = (u16*)(ws + (size_t)(5u << 20));
  float* Op = (float*)(ws + (size_t)(7u << 20));
  float* Mb = (float*)(ws + (size_t)(23u << 20));
  float* Lb = (float*)(ws + (size_t)(23u << 20) + (size_t)NSPLIT * SEQ * 4);
  float* out = (float*)d_out;

  k_wtrans<<<dim3((DIN * DOUT) / 256, 3), 256, 0, stream>>>(wq, wk, wv, Wt);
  k_qkv<<<dim3(SEQ / 32), 128, 0, stream>>>(x, Wt, Q, K, Vt);
  k_attn<<<dim3(SEQ / 64, NSPLIT), 256, 0, stream>>>(Q, K, Vt, Op, Mb, Lb);
  k_combine<<<dim3((SEQ * DOUT) / 256), 256, 0, stream>>>(Op, Mb, Lb, out);
}

// Round 2
// 173.244 us; speedup vs baseline: 1.6461x; 1.6461x over previous
//
#include <hip/hip_runtime.h>
#include <cstdint>

#define SEQ    8192
#define DIN    1024
#define DOUT   128
#define NSPLIT 4
#define KVTILE 64
#define SM_SCALE 0.08838834764831845f   // 1/sqrt(128)
#define LOG2E    1.4426950408889634f

typedef unsigned short u16;
typedef __bf16 bf16x8 __attribute__((ext_vector_type(8)));
typedef float  f32x4  __attribute__((ext_vector_type(4)));
typedef unsigned short u16x8 __attribute__((ext_vector_type(8)));
typedef unsigned short u16x4 __attribute__((ext_vector_type(4)));

// round-to-nearest-even f32 -> bf16
__device__ __forceinline__ u16 f2bf(float f) {
  union { float f; uint32_t u; } c; c.f = f;
  uint32_t u = c.u;
  return (u16)((u + 0x7FFFu + ((u >> 16) & 1u)) >> 16);
}

__device__ __forceinline__ bf16x8 ldsu8(const u16* base, int byteoff) {
  return __builtin_bit_cast(bf16x8,
    *reinterpret_cast<const u16x8*>(reinterpret_cast<const char*>(base) + byteoff));
}
__device__ __forceinline__ bf16x8 glbu8(const u16* p) {
  return __builtin_bit_cast(bf16x8, *reinterpret_cast<const u16x8*>(p));
}

// ---------------------------------------------------------------- kernel 0
// W [1024][128] fp32  ->  Wt [3][128][1024] bf16 (transposed)
__global__ __launch_bounds__(256) void k_wtrans(const float* __restrict__ wq,
                                                const float* __restrict__ wk,
                                                const float* __restrict__ wv,
                                                u16* __restrict__ Wt) {
  const float* w = (blockIdx.y == 0) ? wq : (blockIdx.y == 1) ? wk : wv;
  int idx = blockIdx.x * 256 + threadIdx.x;      // over DIN*DOUT
  int k = idx >> 7, n = idx & 127;
  Wt[(size_t)blockIdx.y * (DOUT * DIN) + (size_t)n * DIN + k] = f2bf(w[idx]);
}

// ---------------------------------------------------------------- kernel 1
// Fused GEMM C[8192][384] = X[8192][1024] * [Wq|Wk|Wv].
// Q,K row-major bf16 [SEQ][128]; V transposed bf16 [128][SEQ].
// Block: 512 threads (8 waves) = 2 m-groups x 4 n-ranges. M-tile 32.
// Each wave: 16 rows x 96 cols, acc = 6 x f32x4 (24 VGPR).
// Grid 256 blocks -> 8 waves/CU (occupancy fix: was 2 waves/CU, 5.8%).
__global__ __launch_bounds__(512) void k_qkv(const float* __restrict__ x,
                                             const u16* __restrict__ Wt,
                                             u16* __restrict__ Q,
                                             u16* __restrict__ K,
                                             u16* __restrict__ Vt) {
  __shared__ __attribute__((aligned(16))) u16 Xs[32 * 64];   // swizzled, 4 KB
  const int tid  = threadIdx.x;
  const int lane = tid & 63, wave = tid >> 6;
  const int lm   = lane & 15, g = lane >> 4;
  const int mg   = wave >> 2;          // 0..1  (m-group: 16 rows each)
  const int nr   = (wave & 3) * 96;    // n-range base (96 cols per wave)
  const int m0   = blockIdx.x * 32;

  f32x4 acc[6];
#pragma unroll
  for (int nb = 0; nb < 6; ++nb) acc[nb] = (f32x4){0.f, 0.f, 0.f, 0.f};

  for (int kc = 0; kc < DIN / 64; ++kc) {
    __syncthreads();
    // stage X tile [32 rows][64 k] fp32 -> bf16, XOR-swizzled (row stride 128B)
    {
      int row = tid >> 4;              // 0..31, one float4 per thread
      int c4  = (tid & 15) * 4;
      float4 v = *reinterpret_cast<const float4*>(
          x + (size_t)(m0 + row) * DIN + kc * 64 + c4);
      u16x4 b = { f2bf(v.x), f2bf(v.y), f2bf(v.z), f2bf(v.w) };
      *reinterpret_cast<u16x4*>(reinterpret_cast<char*>(Xs) + row * 128 +
                                ((c4 * 2) ^ ((row & 7) << 4))) = b;
    }
    __syncthreads();

    const int mrow = mg * 16 + lm;
    bf16x8 a[2];
#pragma unroll
    for (int t = 0; t < 2; ++t)
      a[t] = ldsu8(Xs, mrow * 128 + (((t * 32 + 8 * g) * 2) ^ ((mrow & 7) << 4)));

#pragma unroll
    for (int nb = 0; nb < 6; ++nb) {
      const u16* wp = Wt + (size_t)(nr + nb * 16 + lm) * DIN + kc * 64 + 8 * g;
#pragma unroll
      for (int t = 0; t < 2; ++t) {
        bf16x8 b = glbu8(wp + t * 32);
        acc[nb] = __builtin_amdgcn_mfma_f32_16x16x32_bf16(a[t], b, acc[nb], 0, 0, 0);
      }
    }
  }

  // epilogue: C/D layout col=lane&15, row=(lane>>4)*4+reg  [HW-verified]
  // n-block (16 cols, 16-aligned) never straddles the 128 boundary -> the
  // which-branch is uniform across the wave.
#pragma unroll
  for (int nb = 0; nb < 6; ++nb) {
    int n = nr + nb * 16 + lm;
    int which = n >> 7, col = n & 127;
#pragma unroll
    for (int r = 0; r < 4; ++r) {
      int m = m0 + mg * 16 + g * 4 + r;
      u16 val = f2bf(acc[nb][r]);
      if (which == 0)       Q[(size_t)m * DOUT + col] = val;
      else if (which == 1)  K[(size_t)m * DOUT + col] = val;
      else                  Vt[(size_t)col * SEQ + m] = val;
    }
  }
}

// ---------------------------------------------------------------- kernel 2
// Flash attention partials. Block 256 (4 waves), Q-tile 64 (16 rows/wave),
// KV-tile 64 staged in LDS (XOR-swizzled). grid (SEQ/64, NSPLIT).
__global__ __launch_bounds__(256) void k_attn(const u16* __restrict__ Q,
                                              const u16* __restrict__ K,
                                              const u16* __restrict__ Vt,
                                              float* __restrict__ Op,
                                              float* __restrict__ Mb,
                                              float* __restrict__ Lb) {
  __shared__ __attribute__((aligned(16))) u16 Ks[64 * 128];    // 16 KB
  __shared__ __attribute__((aligned(16))) u16 Vts[128 * 64];   // 16 KB
  __shared__ __attribute__((aligned(16))) u16 Ps[4][16 * 64];  //  8 KB
  const int tid  = threadIdx.x;
  const int lane = tid & 63, wave = tid >> 6;
  const int lm   = lane & 15, g = lane >> 4;
  const int m0   = blockIdx.x * 64;
  const int split = blockIdx.y;
  const int kvbase = split * (SEQ / NSPLIT);

  // Q fragments, resident in registers for the whole kernel
  bf16x8 qf[4];
  {
    const u16* qp = Q + (size_t)(m0 + wave * 16 + lm) * DOUT + 8 * g;
#pragma unroll
    for (int t = 0; t < 4; ++t) qf[t] = glbu8(qp + t * 32);
  }

  f32x4 o[8];
#pragma unroll
  for (int nb = 0; nb < 8; ++nb) o[nb] = (f32x4){0.f, 0.f, 0.f, 0.f};
  float mr[4] = {-1e30f, -1e30f, -1e30f, -1e30f};
  float lr[4] = {0.f, 0.f, 0.f, 0.f};

  for (int it = 0; it < (SEQ / NSPLIT) / KVTILE; ++it) {
    const int kv0 = kvbase + it * KVTILE;
    __syncthreads();
    // stage K tile [64][128] (row stride 256B, swizzle granule = 16B)
#pragma unroll
    for (int p = 0; p < 4; ++p) {
      int row = p * 16 + (tid >> 4), gg = tid & 15;
      u16x8 v = *reinterpret_cast<const u16x8*>(
          K + (size_t)(kv0 + row) * DOUT + gg * 8);
      *reinterpret_cast<u16x8*>(reinterpret_cast<char*>(Ks) + row * 256 +
                                ((gg * 16) ^ ((row & 7) << 4))) = v;
    }
    // stage V^T tile [128][64] (row stride 128B)
#pragma unroll
    for (int p = 0; p < 4; ++p) {
      int n = p * 32 + (tid >> 3), gg = tid & 7;
      u16x8 v = *reinterpret_cast<const u16x8*>(
          Vt + (size_t)n * SEQ + kv0 + gg * 8);
      *reinterpret_cast<u16x8*>(reinterpret_cast<char*>(Vts) + n * 128 +
                                ((gg * 16) ^ ((n & 7) << 4))) = v;
    }
    __syncthreads();

    // ---- S = Q K^T * scale  (4 col-blocks x K=128)
    f32x4 s[4];
#pragma unroll
    for (int cb = 0; cb < 4; ++cb) {
      f32x4 a = (f32x4){0.f, 0.f, 0.f, 0.f};
      int krow = cb * 16 + lm;
#pragma unroll
      for (int t = 0; t < 4; ++t) {
        bf16x8 b = ldsu8(Ks, krow * 256 +
                             (((t * 32 + 8 * g) * 2) ^ ((krow & 7) << 4)));
        a = __builtin_amdgcn_mfma_f32_16x16x32_bf16(qf[t], b, a, 0, 0, 0);
      }
      s[cb] = a * SM_SCALE;
    }

    // ---- online softmax (rows owned by lane: g*4+r; reduce over 16 lanes)
    float pv[4][4];
#pragma unroll
    for (int r = 0; r < 4; ++r) {
      float rm = fmaxf(fmaxf(s[0][r], s[1][r]), fmaxf(s[2][r], s[3][r]));
#pragma unroll
      for (int off = 1; off < 16; off <<= 1) rm = fmaxf(rm, __shfl_xor(rm, off));
      float mn = fmaxf(mr[r], rm);
      float alpha = exp2f((mr[r] - mn) * LOG2E);
      float rs = 0.f;
#pragma unroll
      for (int cb = 0; cb < 4; ++cb) {
        float p = exp2f((s[cb][r] - mn) * LOG2E);
        pv[cb][r] = p;
        rs += p;
      }
#pragma unroll
      for (int off = 1; off < 16; off <<= 1) rs += __shfl_xor(rs, off);
      lr[r] = lr[r] * alpha + rs;
      mr[r] = mn;
#pragma unroll
      for (int nb = 0; nb < 8; ++nb) o[nb][r] *= alpha;
    }

    // ---- P -> per-wave LDS (bf16), swizzled like the others
    u16* pw = Ps[wave];
#pragma unroll
    for (int cb = 0; cb < 4; ++cb)
#pragma unroll
      for (int r = 0; r < 4; ++r) {
        int row = g * 4 + r, col = cb * 16 + lm;
        *reinterpret_cast<u16*>(reinterpret_cast<char*>(pw) + row * 128 +
                                ((col * 2) ^ ((row & 7) << 4))) = f2bf(pv[cb][r]);
      }
    __syncthreads();   // orders P writes before P reads (and is uniform)

    // ---- O += P V   (A = P rows, B = V^T rows = d-columns)
#pragma unroll
    for (int t = 0; t < 2; ++t) {
      bf16x8 pa = ldsu8(pw, lm * 128 +
                            (((t * 32 + 8 * g) * 2) ^ ((lm & 7) << 4)));
#pragma unroll
      for (int nb = 0; nb < 8; ++nb) {
        int vrow = nb * 16 + lm;
        bf16x8 vb = ldsu8(Vts, vrow * 128 +
                              (((t * 32 + 8 * g) * 2) ^ ((vrow & 7) << 4)));
        o[nb] = __builtin_amdgcn_mfma_f32_16x16x32_bf16(pa, vb, o[nb], 0, 0, 0);
      }
    }
  }

  // ---- store partials
  const size_t ob = (size_t)split * SEQ * DOUT;
#pragma unroll
  for (int nb = 0; nb < 8; ++nb)
#pragma unroll
    for (int r = 0; r < 4; ++r) {
      int m = m0 + wave * 16 + g * 4 + r;
      Op[ob + (size_t)m * DOUT + nb * 16 + lm] = o[nb][r];
    }
  if (lm == 0) {
#pragma unroll
    for (int r = 0; r < 4; ++r) {
      int m = m0 + wave * 16 + g * 4 + r;
      Mb[split * SEQ + m] = mr[r];
      Lb[split * SEQ + m] = lr[r];
    }
  }
}

// ---------------------------------------------------------------- kernel 3
__global__ __launch_bounds__(256) void k_combine(const float* __restrict__ Op,
                                                 const float* __restrict__ Mb,
                                                 const float* __restrict__ Lb,
                                                 float* __restrict__ out) {
  int idx = blockIdx.x * 256 + threadIdx.x;   // over SEQ*DOUT
  int srow = idx >> 7;
  float m0 = Mb[srow], m1 = Mb[SEQ + srow], m2 = Mb[2 * SEQ + srow],
        m3 = Mb[3 * SEQ + srow];
  float M = fmaxf(fmaxf(m0, m1), fmaxf(m2, m3));
  float e0 = exp2f((m0 - M) * LOG2E), e1 = exp2f((m1 - M) * LOG2E);
  float e2 = exp2f((m2 - M) * LOG2E), e3 = exp2f((m3 - M) * LOG2E);
  float denom = Lb[srow] * e0 + Lb[SEQ + srow] * e1 + Lb[2 * SEQ + srow] * e2 +
                Lb[3 * SEQ + srow] * e3;
  const size_t st = (size_t)SEQ * DOUT;
  float num = Op[idx] * e0 + Op[st + idx] * e1 + Op[2 * st + idx] * e2 +
              Op[3 * st + idx] * e3;
  out[idx] = num / denom;
}

// ---------------------------------------------------------------- launch
extern "C" void kernel_launch(void* const* d_in, const int* in_sizes, int n_in,
                              void* d_out, int out_size, void* d_ws, size_t ws_size,
                              hipStream_t stream) {
  const float* x  = (const float*)d_in[0];
  const float* wq = (const float*)d_in[1];
  const float* wk = (const float*)d_in[2];
  const float* wv = (const float*)d_in[3];
  char* ws = (char*)d_ws;

  // workspace layout (bytes):
  //  [0,       0xC0000)   Wt bf16 [3][128][1024]
  //  [1 MiB,   3 MiB)     Q  bf16 [8192][128]
  //  [3 MiB,   5 MiB)     K  bf16 [8192][128]
  //  [5 MiB,   7 MiB)     Vt bf16 [128][8192]
  //  [7 MiB,  23 MiB)     Op f32 [4][8192][128]
  //  [23 MiB, +128 KiB)   Mb f32 [4][8192]
  //  [.. ,    +128 KiB)   Lb f32 [4][8192]      total ~23.25 MiB
  u16*   Wt = (u16*)(ws);
  u16*   Q  = (u16*)(ws + (size_t)(1u << 20));
  u16*   K  = (u16*)(ws + (size_t)(3u << 20));
  u16*   Vt = (u16*)(ws + (size_t)(5u << 20));
  float* Op = (float*)(ws + (size_t)(7u << 20));
  float* Mb = (float*)(ws + (size_t)(23u << 20));
  float* Lb = (float*)(ws + (size_t)(23u << 20) + (size_t)NSPLIT * SEQ * 4);
  float* out = (float*)d_out;

  k_wtrans<<<dim3((DIN * DOUT) / 256, 3), 256, 0, stream>>>(wq, wk, wv, Wt);
  k_qkv<<<dim3(SEQ / 32), 512, 0, stream>>>(x, Wt, Q, K, Vt);
  k_attn<<<dim3(SEQ / 64, NSPLIT), 256, 0, stream>>>(Q, K, Vt, Op, Mb, Lb);
  k_combine<<<dim3((SEQ * DOUT) / 256), 256, 0, stream>>>(Op, Mb, Lb, out);
}